// Round 4
// baseline (348.567 us; speedup 1.0000x reference)
//
#include <hip/hip_runtime.h>
#include <math.h>

// Problem constants (fixed-shape problem)
#define B_  16
#define D_  37
#define F_  4096
#define I_  64
#define EPS 1e-5f
// softmax scale 1/sqrt(64) folded with log2(e) into q at projection time,
// so S_mfma = att*log2e and softmax is a raw exp2. |att|<=8 (LN rows have
// norm exactly 8) -> exp2(S) <= 2^11.6: no max pass, bf16-safe unnormalized P.
#define QSCALE 0.18033688011112042f
#define NQS 4           // stats q-split (partial-Z planes)
#define NKS 4           // out k-split (1 f32 out + 3 f32 partial planes)

typedef unsigned short u16;
typedef __bf16 bf16x8 __attribute__((ext_vector_type(8)));
typedef __bf16 bf16x2v __attribute__((ext_vector_type(2)));
typedef float  f32x16 __attribute__((ext_vector_type(16)));
typedef float  f32x2v __attribute__((ext_vector_type(2)));
typedef unsigned int u32x4 __attribute__((ext_vector_type(4)));
typedef int i32x2 __attribute__((ext_vector_type(2)));

#define ZERO16 {0,0,0,0, 0,0,0,0, 0,0,0,0, 0,0,0,0}
#define MFMA32(a, b, c) __builtin_amdgcn_mfma_f32_32x32x16_bf16((a), (b), (c), 0, 0, 0)

#if __has_builtin(__builtin_amdgcn_exp2f)
#define EX2(x) __builtin_amdgcn_exp2f(x)
#else
#define EX2(x) exp2f(x)
#endif
#if __has_builtin(__builtin_amdgcn_rcpf)
#define RCP(x) __builtin_amdgcn_rcpf(x)
#else
#define RCP(x) (1.f / (x))
#endif

// fp32 -> bf16 RNE (scalar)
__device__ __forceinline__ u16 f2b(float f) {
  unsigned u = __builtin_bit_cast(unsigned, f);
  return (u16)((u + 0x7fffu + ((u >> 16) & 1u)) >> 16);
}
// bf16 bits -> fp32
__device__ __forceinline__ float b2f(u16 h) {
  return __builtin_bit_cast(float, (unsigned)h << 16);
}
// pack two fp32 -> bf16x2 (one v_cvt_pk_bf16_f32 where available)
__device__ __forceinline__ unsigned pk2(float lo, float hi) {
  f32x2v f = {lo, hi};
  bf16x2v h = __builtin_convertvector(f, bf16x2v);
  return __builtin_bit_cast(unsigned, h);
}

// half-wave register swap (v_permlane32_swap_b32 on gfx950)
__device__ __forceinline__ void plswap(unsigned& a, unsigned& b) {
#if __has_builtin(__builtin_amdgcn_permlane32_swap)
  i32x2 r = __builtin_amdgcn_permlane32_swap((int)a, (int)b, false, false);
  a = (unsigned)r[0];
  b = (unsigned)r[1];
#else
  const int lh = (int)((threadIdx.x & 63) >> 5);
  unsigned pa = (unsigned)__shfl_xor((int)a, 32, 64);
  unsigned pb = (unsigned)__shfl_xor((int)b, 32, 64);
  unsigned na = lh ? pb : a;
  unsigned nb = lh ? b : pa;
  a = na;
  b = nb;
#endif
}

// From one S^T 32x32 C-block (rows=k, cols=q), build two PV A-fragments
// (m=q, contraction k): f0 = k 0..15, f1 = k 16..31 of this block.
// C-reg r holds k=(r&3)+8*(r>>2)+4*lh; A-frag VGPR j needs k=lh*8+2j(+1).
__device__ __forceinline__ void build_af(const f32x16& s, bf16x8& f0, bf16x8& f1) {
  float e[16];
#pragma unroll
  for (int r = 0; r < 16; ++r) e[r] = EX2(s[r]);
  unsigned a = pk2(e[0], e[1]),   bq = pk2(e[2], e[3]);
  unsigned c = pk2(e[4], e[5]),   d  = pk2(e[6], e[7]);
  plswap(a, c);
  plswap(bq, d);
  u32x4 v0 = {a, bq, c, d};
  f0 = __builtin_bit_cast(bf16x8, v0);
  unsigned ee = pk2(e[8], e[9]),  ff = pk2(e[10], e[11]);
  unsigned g  = pk2(e[12], e[13]), h = pk2(e[14], e[15]);
  plswap(ee, g);
  plswap(ff, h);
  u32x4 v1 = {ee, ff, g, h};
  f1 = __builtin_bit_cast(bf16x8, v1);
}

// XCD-chunked bijective block swizzle for 1024-block 1-D grids (8 XCDs x
// 128): hardware round-robins dispatch index over XCDs, so giving XCD x the
// contiguous logical range [x*128, x*128+128) clusters blocks that stream
// the same K/V (or Q) panels onto one XCD's L2.
__device__ __forceinline__ int swz1024(int wg) {
  return (wg & 7) * 128 + (wg >> 3);
}

// ---------------------------------------------------------------------------
// Kernel 1: qkv projection + LayerNorm -> bf16. q pre-scaled by QSCALE.
// v written transposed vt[b][i][f] for the out kernel's B-fragments.
// ---------------------------------------------------------------------------
__global__ __launch_bounds__(256) void qkv_ln_k(
    const float* __restrict__ x,
    const float* __restrict__ Wq, const float* __restrict__ Wk,
    const float* __restrict__ Wv,
    u16* __restrict__ qn, u16* __restrict__ kn, u16* __restrict__ vt) {
  __shared__ float sW[3 * D_ * I_];
  __shared__ float xs[D_ * 64];
  __shared__ __align__(16) u16 vtile[64 * 72];

  const int t = threadIdx.x;
  const int b = blockIdx.y;
  const int f0 = blockIdx.x * 64;

  for (int i = t; i < D_ * I_; i += 256) {
    sW[i]               = Wq[i];
    sW[D_ * I_ + i]     = Wk[i];
    sW[2 * D_ * I_ + i] = Wv[i];
  }
  const float* xb = x + (size_t)b * D_ * F_ + f0;
  for (int i = t; i < D_ * 64; i += 256)
    xs[i] = xb[(size_t)(i >> 6) * F_ + (i & 63)];
  __syncthreads();

  const int lane = t & 63, w = t >> 6;

  for (int it = 0; it < 16; ++it) {
    const int fl = w * 16 + it;
    float hq = 0.f, hk = 0.f, hv = 0.f;
#pragma unroll
    for (int d = 0; d < D_; ++d) {
      const float xv = xs[d * 64 + fl];
      hq = fmaf(xv, sW[d * 64 + lane], hq);
      hk = fmaf(xv, sW[D_ * I_ + d * 64 + lane], hk);
      hv = fmaf(xv, sW[2 * D_ * I_ + d * 64 + lane], hv);
    }
    auto lnorm = [&](float a) -> float {
      float s = a;
#pragma unroll
      for (int o = 32; o > 0; o >>= 1) s += __shfl_xor(s, o, 64);
      const float mu = s * (1.f / 64.f);
      const float d0 = a - mu;
      float v = d0 * d0;
#pragma unroll
      for (int o = 32; o > 0; o >>= 1) v += __shfl_xor(v, o, 64);
      return d0 * rsqrtf(v * (1.f / 64.f) + EPS);
    };
    const size_t fo = ((size_t)b * F_ + f0 + fl) * I_ + lane;
    qn[fo] = f2b(lnorm(hq) * QSCALE);
    kn[fo] = f2b(lnorm(hk));
    vtile[lane * 72 + fl] = f2b(lnorm(hv));
  }
  __syncthreads();
  for (int p = 0; p < 2; ++p) {
    const int c = p * 256 + t;
    const int r = c >> 3, off = (c & 7) * 8;
    const int4 v = *(const int4*)&vtile[r * 72 + off];
    *(int4*)(vt + ((size_t)b * I_ + r) * F_ + f0 + off) = v;
  }
}

// ---------------------------------------------------------------------------
// Kernel 2: partial column-softmax sums zp[qh][b][k] = sum_{q in quarter}
// exp2(S). NO LDS, NO BARRIERS: rounds 1-3 proved the chunk-barrier lockstep
// is the latency bottleneck (per-SIMD MFMA occupancy only ~9%) and every
// occupancy fix through LDS/registers traded away the gain. K/Q panels are
// L2-resident (XCD swizzle), so each wave hoists its own K fragments and
// streams Q fragments straight global->VGPR (identical 16B/lane fragments;
// 128B rows shared across ic -> one line fetch, L1-reused across waves).
// Waves free-run; TLP hides L2 latency. Regs ~125 -> (256,3), 12 waves/CU.
// ---------------------------------------------------------------------------
__global__ __launch_bounds__(256, 3) void attn_stats_k(
    const u16* __restrict__ qn, const u16* __restrict__ kn,
    float* __restrict__ zp) {
  const int t = threadIdx.x, lane = t & 63, w = t >> 6;
  const int l31 = lane & 31, lh = lane >> 5;
  // XCD-chunked decode: 16 consecutive logical ids share (b,qh).
  const int lg = swz1024((int)blockIdx.x);
  const int k0 = (lg & 15) * 256, b = (lg >> 4) & 15, qh = lg >> 8;

  // hoist own 64-k B-fragments directly from global (one-time, 8 loads)
  const u16* kp = kn + ((size_t)b * F_ + k0 + w * 64 + l31) * I_ + lh * 8;
  bf16x8 kf[2][4];
#pragma unroll
  for (int kb2 = 0; kb2 < 2; ++kb2)
#pragma unroll
    for (int ic = 0; ic < 4; ++ic)
      kf[kb2][ic] = *(const bf16x8*)(kp + kb2 * 32 * I_ + ic * 16);

  // Q stream base (this wave reads the same Q as the others -> L1 reuse)
  const u16* qp = qn + ((size_t)b * F_ + qh * (F_ / NQS) + l31) * I_ + lh * 8;

  float Zc[2][2] = {{0.f, 0.f}, {0.f, 0.f}};  // [qb][kb]
  const int NC = F_ / NQS / 64;             // 16 chunks

  for (int c = 0; c < NC; ++c) {
    f32x16 a00 = ZERO16, a01 = ZERO16, a10 = ZERO16, a11 = ZERO16;
    __builtin_amdgcn_s_setprio(1);
#pragma unroll
    for (int ic = 0; ic < 4; ++ic) {
      const bf16x8 q0f = *(const bf16x8*)(qp + ic * 16);
      const bf16x8 q1f = *(const bf16x8*)(qp + 32 * I_ + ic * 16);
      a00 = MFMA32(q0f, kf[0][ic], a00);
      a01 = MFMA32(q0f, kf[1][ic], a01);
      a10 = MFMA32(q1f, kf[0][ic], a10);
      a11 = MFMA32(q1f, kf[1][ic], a11);
    }
    __builtin_amdgcn_s_setprio(0);
#pragma unroll
    for (int r = 0; r < 16; ++r) {
      Zc[0][0] += EX2(a00[r]);
      Zc[0][1] += EX2(a01[r]);
      Zc[1][0] += EX2(a10[r]);
      Zc[1][1] += EX2(a11[r]);
    }
    qp += 64 * I_;
  }

#pragma unroll
  for (int kb2 = 0; kb2 < 2; ++kb2) {
    float Zt = Zc[0][kb2] + Zc[1][kb2];
    Zt += __shfl_xor(Zt, 32, 64);
    if (lane < 32)
      zp[((size_t)qh * B_ + b) * F_ + k0 + w * 64 + kb2 * 32 + lane] = Zt;
  }
}

// ---------------------------------------------------------------------------
// Kernel 3: fold 1/Z_k into V rows, in place: vt[b][i][k] *= 1/sum_qh zp.
// ---------------------------------------------------------------------------
__global__ __launch_bounds__(256) void vscale_k(u16* __restrict__ vt,
                                                const float* __restrict__ zp) {
  const int b = blockIdx.y;
  const int off = (blockIdx.x * 256 + (int)threadIdx.x) * 8;  // within I_*F_
  const int k = off & (F_ - 1);
  const size_t BF = (size_t)B_ * F_;
  u16* p = vt + (size_t)b * I_ * F_ + off;
  const float* z = zp + (size_t)b * F_ + k;
  int4 raw = *(const int4*)p;
  u16 es[8], os[8];
  *(int4*)es = raw;
#pragma unroll
  for (int j = 0; j < 8; ++j) {
    const float v = b2f(es[j]);
    float zs = 0.f;
#pragma unroll
    for (int qh = 0; qh < NQS; ++qh) zs += z[qh * BF + j];
    os[j] = f2b(v * RCP(zs));
  }
  *(int4*)p = *(int4*)os;
}

// ---------------------------------------------------------------------------
// Kernel 4: partial out over a k-quarter: out[q,i] = sum_{k in qtr} exp2(S)
// * v'. NO LDS, NO BARRIERS (see kernel 2 rationale): per 64-k chunk each
// wave loads its K fragments (8x16B) and V fragments (8x16B) straight from
// L2/L1 -- the (b,ks) K/V quarter is 256 KB and L2-resident via the XCD
// swizzle, and the block's 4 waves share lines in L1. Waves free-run; no
// lockstep, no staging registers, no bank conflicts. Per-chunk: S^T (A=K,
// 8 MFMA per k-half) -> exp2 + in-register transpose -> PV. Persistent regs
// o(64)+qf(32)=96, transient ~50 -> ~150 fits (256,3) with margin (round
// 3's spill was a true-liveness ~180 vs cap 170; watch WRITE_SIZE ~67 MB
// as the no-spill check). ks=0 -> f32 out; ks>0 -> f32 partial plane.
// ---------------------------------------------------------------------------
__global__ __launch_bounds__(256, 3) void attn_out_k(
    const u16* __restrict__ qn, const u16* __restrict__ kn,
    const u16* __restrict__ vt, float* __restrict__ out,
    float* __restrict__ pp) {
  const int t = threadIdx.x, lane = t & 63, w = t >> 6;
  const int l31 = lane & 31, lh = lane >> 5;
  // XCD-chunked decode: 16 consecutive logical ids share (b,ks).
  const int lg = swz1024((int)blockIdx.x);
  const int q0 = (lg & 15) * 256, b = (lg >> 4) & 15, ks = lg >> 8;
  const int kbase = ks * (F_ / NKS);

  // hoist own 64-q B-fragments directly from global (one-time, 8 loads)
  const u16* qp = qn + ((size_t)b * F_ + q0 + w * 64 + l31) * I_ + lh * 8;
  bf16x8 qf[2][4];
#pragma unroll
  for (int qb2 = 0; qb2 < 2; ++qb2)
#pragma unroll
    for (int ic = 0; ic < 4; ++ic)
      qf[qb2][ic] = *(const bf16x8*)(qp + qb2 * 32 * I_ + ic * 16);

  // K fragment stream: kh=0/1 bases, advance 64 rows (64*I_ elems) per chunk
  const u16* kp0 = kn + ((size_t)b * F_ + kbase + l31) * I_ + lh * 8;
  const u16* kp1 = kp0 + 32 * I_;
  // V fragment stream: ih=0/1 bases (vt rows are i), advance 64 k per chunk
  const u16* vp0 = vt + ((size_t)b * I_ + l31) * F_ + kbase + lh * 8;
  const u16* vp1 = vp0 + (size_t)32 * F_;

  f32x16 o00 = ZERO16, o01 = ZERO16, o10 = ZERO16, o11 = ZERO16; // [qb][ih]
  const int NC = F_ / NKS / 64;             // 16 chunks in this k-quarter

  for (int c = 0; c < NC; ++c) {
    // ---- k-half 0 (K rows 0..31): S -> exp2/transpose -> PV k 0..31 ----
    {
      f32x16 s0 = ZERO16, s1 = ZERO16;      // [qb]
      __builtin_amdgcn_s_setprio(1);
#pragma unroll
      for (int ic = 0; ic < 4; ++ic) {
        const bf16x8 ak = *(const bf16x8*)(kp0 + ic * 16);
        s0 = MFMA32(ak, qf[0][ic], s0);
        s1 = MFMA32(ak, qf[1][ic], s1);
      }
      __builtin_amdgcn_s_setprio(0);
      bf16x8 af[2][2];
      build_af(s0, af[0][0], af[0][1]);
      build_af(s1, af[1][0], af[1][1]);
      __builtin_amdgcn_s_setprio(1);
#pragma unroll
      for (int kb4 = 0; kb4 < 2; ++kb4) {
        const bf16x8 bv0 = *(const bf16x8*)(vp0 + kb4 * 16);
        const bf16x8 bv1 = *(const bf16x8*)(vp1 + kb4 * 16);
        o00 = MFMA32(af[0][kb4], bv0, o00);
        o01 = MFMA32(af[0][kb4], bv1, o01);
        o10 = MFMA32(af[1][kb4], bv0, o10);
        o11 = MFMA32(af[1][kb4], bv1, o11);
      }
      __builtin_amdgcn_s_setprio(0);
    }

    // ---- k-half 1 (K rows 32..63): S -> exp2/transpose -> PV k 32..63 ----
    {
      f32x16 s0 = ZERO16, s1 = ZERO16;      // [qb]
      __builtin_amdgcn_s_setprio(1);
#pragma unroll
      for (int ic = 0; ic < 4; ++ic) {
        const bf16x8 ak = *(const bf16x8*)(kp1 + ic * 16);
        s0 = MFMA32(ak, qf[0][ic], s0);
        s1 = MFMA32(ak, qf[1][ic], s1);
      }
      __builtin_amdgcn_s_setprio(0);
      bf16x8 af[2][2];
      build_af(s0, af[0][0], af[0][1]);
      build_af(s1, af[1][0], af[1][1]);
      __builtin_amdgcn_s_setprio(1);
#pragma unroll
      for (int kb4 = 2; kb4 < 4; ++kb4) {
        const bf16x8 bv0 = *(const bf16x8*)(vp0 + kb4 * 16);
        const bf16x8 bv1 = *(const bf16x8*)(vp1 + kb4 * 16);
        o00 = MFMA32(af[0][kb4 - 2], bv0, o00);
        o01 = MFMA32(af[0][kb4 - 2], bv1, o01);
        o10 = MFMA32(af[1][kb4 - 2], bv0, o10);
        o11 = MFMA32(af[1][kb4 - 2], bv1, o11);
      }
      __builtin_amdgcn_s_setprio(0);
    }

    kp0 += 64 * I_;
    kp1 += 64 * I_;
    vp0 += 64;
    vp1 += 64;
  }

  float* ob = (ks == 0 ? out
                       : pp + (size_t)(ks - 1) * ((size_t)B_ * F_ * I_)) +
              ((size_t)b * F_ + q0 + w * 64) * I_;
#pragma unroll
  for (int r = 0; r < 16; ++r) {
    const int qr = (r & 3) + 8 * (r >> 2) + 4 * lh;     // C/D row mapping
    ob[(size_t)qr * I_ + l31]              = o00[r];
    ob[(size_t)qr * I_ + 32 + l31]         = o01[r];
    ob[(size_t)(32 + qr) * I_ + l31]       = o10[r];
    ob[(size_t)(32 + qr) * I_ + 32 + l31]  = o11[r];
  }
}

// ---------------------------------------------------------------------------
// Kernel 5: out += 3 f32 partial planes (k-split reduction). 8 elems/thread.
// ---------------------------------------------------------------------------
__global__ __launch_bounds__(256) void reduce_k(float* __restrict__ out,
                                                const float* __restrict__ pp) {
  const size_t NBF = (size_t)B_ * F_ * I_;
  const size_t i = ((size_t)blockIdx.x * 256 + threadIdx.x) * 8;
  float4 a0 = *(const float4*)(out + i);
  float4 a1 = *(const float4*)(out + i + 4);
#pragma unroll
  for (int pl = 0; pl < NKS - 1; ++pl) {
    const float* q = pp + (size_t)pl * NBF + i;
    const float4 b0 = *(const float4*)q;
    const float4 b1 = *(const float4*)(q + 4);
    a0.x += b0.x; a0.y += b0.y; a0.z += b0.z; a0.w += b0.w;
    a1.x += b1.x; a1.y += b1.y; a1.z += b1.z; a1.w += b1.w;
  }
  *(float4*)(out + i)     = a0;
  *(float4*)(out + i + 4) = a1;
}

// ---------------------------------------------------------------------------
extern "C" void kernel_launch(void* const* d_in, const int* in_sizes, int n_in,
                              void* d_out, int out_size, void* d_ws,
                              size_t ws_size, hipStream_t stream) {
  const float* x  = (const float*)d_in[0];
  const float* Wq = (const float*)d_in[1];
  const float* Wk = (const float*)d_in[2];
  const float* Wv = (const float*)d_in[3];
  float* out = (float*)d_out;

  // workspace: qn, kn, vt (bf16, B*F*I each); zp (f32 [NQS][B][F]);
  //            pp (f32 [NKS-1][B][F][I] k-split partial planes)
  const size_t NBF = (size_t)B_ * F_ * I_;
  u16* qn   = (u16*)d_ws;
  u16* kn   = qn + NBF;
  u16* vt   = kn + NBF;
  float* zp = (float*)(vt + NBF);
  float* pp = zp + (size_t)NQS * B_ * F_;

  qkv_ln_k<<<dim3(F_ / 64, B_), 256, 0, stream>>>(x, Wq, Wk, Wv, qn, kn, vt);
  // 1024 blocks, XCD-chunked swizzle (16 k-tiles x 16 b x NQS q-quarters)
  attn_stats_k<<<dim3(1024), 256, 0, stream>>>(qn, kn, zp);
  vscale_k<<<dim3(I_ * F_ / 2048, B_), 256, 0, stream>>>(vt, zp);
  // 1024 blocks, XCD-chunked swizzle (16 q-tiles x 16 b x NKS k-quarters)
  attn_out_k<<<dim3(1024), 256, 0, stream>>>(qn, kn, vt, out, pp);
  reduce_k<<<dim3((int)(NBF / 2048)), 256, 0, stream>>>(out, pp);
}

// Round 6
// 232.894 us; speedup vs baseline: 1.4967x; 1.4967x over previous
//
#include <hip/hip_runtime.h>
#include <math.h>

// Problem constants (fixed-shape problem)
#define B_  16
#define D_  37
#define F_  4096
#define I_  64
#define EPS 1e-5f
// softmax scale 1/sqrt(64) folded with log2(e) into q at projection time,
// so S_mfma = att*log2e and softmax is a raw exp2. |att|<=8 (LN rows have
// norm exactly 8) -> exp2(S) <= 2^11.6: no max pass, bf16-safe unnormalized P.
#define QSCALE 0.18033688011112042f
#define NQS 2           // stats q-split (partial-Z planes)
#define NKS 2           // out k-split (f32 out + bf16 partial)

typedef unsigned short u16;
typedef __bf16 bf16x8 __attribute__((ext_vector_type(8)));
typedef __bf16 bf16x2v __attribute__((ext_vector_type(2)));
typedef float  f32x16 __attribute__((ext_vector_type(16)));
typedef float  f32x2v __attribute__((ext_vector_type(2)));
typedef unsigned int u32x4 __attribute__((ext_vector_type(4)));
typedef int i32x2 __attribute__((ext_vector_type(2)));

#define ZERO16 {0,0,0,0, 0,0,0,0, 0,0,0,0, 0,0,0,0}
#define MFMA32(a, b, c) __builtin_amdgcn_mfma_f32_32x32x16_bf16((a), (b), (c), 0, 0, 0)

#if __has_builtin(__builtin_amdgcn_exp2f)
#define EX2(x) __builtin_amdgcn_exp2f(x)
#else
#define EX2(x) exp2f(x)
#endif
#if __has_builtin(__builtin_amdgcn_rcpf)
#define RCP(x) __builtin_amdgcn_rcpf(x)
#else
#define RCP(x) (1.f / (x))
#endif

// fp32 -> bf16 RNE (scalar)
__device__ __forceinline__ u16 f2b(float f) {
  unsigned u = __builtin_bit_cast(unsigned, f);
  return (u16)((u + 0x7fffu + ((u >> 16) & 1u)) >> 16);
}
// bf16 bits -> fp32
__device__ __forceinline__ float b2f(u16 h) {
  return __builtin_bit_cast(float, (unsigned)h << 16);
}
// pack two fp32 -> bf16x2 (one v_cvt_pk_bf16_f32 where available)
__device__ __forceinline__ unsigned pk2(float lo, float hi) {
  f32x2v f = {lo, hi};
  bf16x2v h = __builtin_convertvector(f, bf16x2v);
  return __builtin_bit_cast(unsigned, h);
}

// half-wave register swap (v_permlane32_swap_b32 on gfx950)
__device__ __forceinline__ void plswap(unsigned& a, unsigned& b) {
#if __has_builtin(__builtin_amdgcn_permlane32_swap)
  i32x2 r = __builtin_amdgcn_permlane32_swap((int)a, (int)b, false, false);
  a = (unsigned)r[0];
  b = (unsigned)r[1];
#else
  const int lh = (int)((threadIdx.x & 63) >> 5);
  unsigned pa = (unsigned)__shfl_xor((int)a, 32, 64);
  unsigned pb = (unsigned)__shfl_xor((int)b, 32, 64);
  unsigned na = lh ? pb : a;
  unsigned nb = lh ? b : pa;
  a = na;
  b = nb;
#endif
}

// From one S^T 32x32 C-block (rows=k, cols=q), build two PV A-fragments
// (m=q, contraction k): f0 = k 0..15, f1 = k 16..31 of this block.
// C-reg r holds k=(r&3)+8*(r>>2)+4*lh; A-frag VGPR j needs k=lh*8+2j(+1).
__device__ __forceinline__ void build_af(const f32x16& s, bf16x8& f0, bf16x8& f1) {
  float e[16];
#pragma unroll
  for (int r = 0; r < 16; ++r) e[r] = EX2(s[r]);
  unsigned a = pk2(e[0], e[1]),   bq = pk2(e[2], e[3]);
  unsigned c = pk2(e[4], e[5]),   d  = pk2(e[6], e[7]);
  plswap(a, c);
  plswap(bq, d);
  u32x4 v0 = {a, bq, c, d};
  f0 = __builtin_bit_cast(bf16x8, v0);
  unsigned ee = pk2(e[8], e[9]),  ff = pk2(e[10], e[11]);
  unsigned g  = pk2(e[12], e[13]), h = pk2(e[14], e[15]);
  plswap(ee, g);
  plswap(ff, h);
  u32x4 v1 = {ee, ff, g, h};
  f1 = __builtin_bit_cast(bf16x8, v1);
}

// ---------------------------------------------------------------------------
// Swizzled LDS tiles: logical [rows][64] bf16, elem (r,c) at
//   r*64 + ((c>>3 ^ (r&7))<<3) + (c&7)
// -> 16B-aligned b128 reads AND conflict-free banks without padding.
// ---------------------------------------------------------------------------
__device__ __forceinline__ bf16x8 ldfrag(const u16* base, int row, int kb) {
  return *(const bf16x8*)(base + (row << 6) + ((kb ^ (row & 7)) << 3));
}
// hoisted-staging helpers: LDS offset and global offset for chunk index c
__device__ __forceinline__ int soff_l(int c) {
  const int r = c >> 3, cb = c & 7;
  return (r << 6) + ((cb ^ (r & 7)) << 3);
}
__device__ __forceinline__ int soff_g(int c, int spitch) {
  return (c >> 3) * spitch + ((c & 7) << 3);
}

// XCD-chunked bijective block swizzle for 512-block 1-D grids (8 XCDs x 64):
// clusters blocks that stream the same K/V (or Q) panels onto one XCD's L2.
__device__ __forceinline__ int swz512(int wg) {
  return (wg & 7) * 64 + (wg >> 3);
}

// ---------------------------------------------------------------------------
// Kernel 1: qkv projection + LayerNorm -> bf16. q pre-scaled by QSCALE.
// v written transposed vt[b][i][f] for the out kernel's B-fragments.
// ---------------------------------------------------------------------------
__global__ __launch_bounds__(256) void qkv_ln_k(
    const float* __restrict__ x,
    const float* __restrict__ Wq, const float* __restrict__ Wk,
    const float* __restrict__ Wv,
    u16* __restrict__ qn, u16* __restrict__ kn, u16* __restrict__ vt) {
  __shared__ float sW[3 * D_ * I_];
  __shared__ float xs[D_ * 64];
  __shared__ __align__(16) u16 vtile[64 * 72];

  const int t = threadIdx.x;
  const int b = blockIdx.y;
  const int f0 = blockIdx.x * 64;

  for (int i = t; i < D_ * I_; i += 256) {
    sW[i]               = Wq[i];
    sW[D_ * I_ + i]     = Wk[i];
    sW[2 * D_ * I_ + i] = Wv[i];
  }
  const float* xb = x + (size_t)b * D_ * F_ + f0;
  for (int i = t; i < D_ * 64; i += 256)
    xs[i] = xb[(size_t)(i >> 6) * F_ + (i & 63)];
  __syncthreads();

  const int lane = t & 63, w = t >> 6;

  for (int it = 0; it < 16; ++it) {
    const int fl = w * 16 + it;
    float hq = 0.f, hk = 0.f, hv = 0.f;
#pragma unroll
    for (int d = 0; d < D_; ++d) {
      const float xv = xs[d * 64 + fl];
      hq = fmaf(xv, sW[d * 64 + lane], hq);
      hk = fmaf(xv, sW[D_ * I_ + d * 64 + lane], hk);
      hv = fmaf(xv, sW[2 * D_ * I_ + d * 64 + lane], hv);
    }
    auto lnorm = [&](float a) -> float {
      float s = a;
#pragma unroll
      for (int o = 32; o > 0; o >>= 1) s += __shfl_xor(s, o, 64);
      const float mu = s * (1.f / 64.f);
      const float d0 = a - mu;
      float v = d0 * d0;
#pragma unroll
      for (int o = 32; o > 0; o >>= 1) v += __shfl_xor(v, o, 64);
      return d0 * rsqrtf(v * (1.f / 64.f) + EPS);
    };
    const size_t fo = ((size_t)b * F_ + f0 + fl) * I_ + lane;
    qn[fo] = f2b(lnorm(hq) * QSCALE);
    kn[fo] = f2b(lnorm(hk));
    vtile[lane * 72 + fl] = f2b(lnorm(hv));
  }
  __syncthreads();
  for (int p = 0; p < 2; ++p) {
    const int c = p * 256 + t;
    const int r = c >> 3, off = (c & 7) * 8;
    const int4 v = *(const int4*)&vtile[r * 72 + off];
    *(int4*)(vt + ((size_t)b * I_ + r) * F_ + f0 + off) = v;
  }
}

// ---------------------------------------------------------------------------
// Kernel 2: partial column-softmax sums zp[qh][b][k] = sum_{q in half}
// exp2(S). Reframe (r5): at 2-phase structure the limiter is the per-chunk
// stage->barrier stall (m233), so this version amortizes it: DOUBLE-CHUNK
// phases (128 q staged per barrier as two 64-q sub-tiles; barriers halve)
// with sub-granular T14 (loads issued under the other sub's compute, <=8
// staging regs). K fragments hoisted direct global->VGPR (r4-verified) --
// no initial LDS K-stage. Staging itself is the r2-proven reg-staged path.
// ---------------------------------------------------------------------------
__global__ __launch_bounds__(256, 2) void attn_stats_k(
    const u16* __restrict__ qn, const u16* __restrict__ kn,
    float* __restrict__ zp) {
  __shared__ __align__(16) u16 sm[16384];   // 32 KB: Q dbuf 2 x (2 x 4096)

  const int t = threadIdx.x, lane = t & 63, w = t >> 6;
  const int l31 = lane & 31, lh = lane >> 5;
  // XCD-chunked decode: 16 consecutive logical ids share (b,qh).
  const int lg = swz512((int)blockIdx.x);
  const int k0 = (lg & 15) * 256, b = (lg >> 4) & 15, qh = lg >> 8;

  // hoist own 64-k B-fragments directly from global (one-time, 8 loads)
  const u16* kp = kn + ((size_t)b * F_ + k0 + w * 64 + l31) * I_ + lh * 8;
  bf16x8 kf[2][4];
#pragma unroll
  for (int kb2 = 0; kb2 < 2; ++kb2)
#pragma unroll
    for (int ic = 0; ic < 4; ++ic)
      kf[kb2][ic] = *(const bf16x8*)(kp + kb2 * 32 * I_ + ic * 16);

  // hoisted Q staging offsets (2 chunks16B per thread per 64-q sub-tile)
  int qoff_l[2], qoff_g[2];
#pragma unroll
  for (int p = 0; p < 2; ++p) {
    const int c = p * 256 + t;
    qoff_l[p] = soff_l(c);
    qoff_g[p] = soff_g(c, 64);
  }

  const u16* qsrc = qn + ((size_t)b * F_ + qh * (F_ / NQS)) * I_;
  // prologue: stage phase 0 (both subs) into buffer 0
#pragma unroll
  for (int s = 0; s < 2; ++s)
#pragma unroll
    for (int p = 0; p < 2; ++p)
      *(int4*)(sm + s * 4096 + qoff_l[p]) =
          *(const int4*)(qsrc + s * 64 * I_ + qoff_g[p]);
  qsrc += 128 * I_;

  float Zc[2][2] = {{0.f, 0.f}, {0.f, 0.f}};  // [qb][kb]

  auto qcompute = [&](const u16* Qc) {
    f32x16 a00 = ZERO16, a01 = ZERO16, a10 = ZERO16, a11 = ZERO16;
    __builtin_amdgcn_s_setprio(1);
#pragma unroll
    for (int ic = 0; ic < 4; ++ic) {
      const bf16x8 q0f = ldfrag(Qc, l31, ic * 2 + lh);
      const bf16x8 q1f = ldfrag(Qc + 32 * 64, l31, ic * 2 + lh);
      a00 = MFMA32(q0f, kf[0][ic], a00);
      a01 = MFMA32(q0f, kf[1][ic], a01);
      a10 = MFMA32(q1f, kf[0][ic], a10);
      a11 = MFMA32(q1f, kf[1][ic], a11);
    }
    __builtin_amdgcn_s_setprio(0);
#pragma unroll
    for (int r = 0; r < 16; ++r) {
      Zc[0][0] += EX2(a00[r]);
      Zc[0][1] += EX2(a01[r]);
      Zc[1][0] += EX2(a10[r]);
      Zc[1][1] += EX2(a11[r]);
    }
  };

  const int NC = F_ / NQS / 128;            // 16 double-chunk phases

  for (int c = 0; c < NC; ++c) {
    const int cur = (c & 1) * 8192;
    const int nxt = cur ^ 8192;
    const bool pf = (c + 1 < NC);
    __syncthreads();                        // cur staged; nxt's readers done
    int4 qr0, qr1;
    if (pf) {                               // T14: sub0' loads under compute
      qr0 = *(const int4*)(qsrc + qoff_g[0]);
      qr1 = *(const int4*)(qsrc + qoff_g[1]);
    }
    qcompute(sm + cur);                     // sub 0
    if (pf) {
      *(int4*)(sm + nxt + qoff_l[0]) = qr0;
      *(int4*)(sm + nxt + qoff_l[1]) = qr1;
      qr0 = *(const int4*)(qsrc + 64 * I_ + qoff_g[0]);
      qr1 = *(const int4*)(qsrc + 64 * I_ + qoff_g[1]);
    }
    qcompute(sm + cur + 4096);              // sub 1
    if (pf) {
      *(int4*)(sm + nxt + 4096 + qoff_l[0]) = qr0;
      *(int4*)(sm + nxt + 4096 + qoff_l[1]) = qr1;
      qsrc += 128 * I_;
    }
  }

#pragma unroll
  for (int kb2 = 0; kb2 < 2; ++kb2) {
    float Zt = Zc[0][kb2] + Zc[1][kb2];
    Zt += __shfl_xor(Zt, 32, 64);
    if (lane < 32)
      zp[((size_t)qh * B_ + b) * F_ + k0 + w * 64 + kb2 * 32 + lane] = Zt;
  }
}

// ---------------------------------------------------------------------------
// Kernel 3: fold 1/Z_k into V rows, in place: vt[b][i][k] *= 1/sum_qh zp.
// ---------------------------------------------------------------------------
__global__ __launch_bounds__(256) void vscale_k(u16* __restrict__ vt,
                                                const float* __restrict__ zp) {
  const int b = blockIdx.y;
  const int off = (blockIdx.x * 256 + (int)threadIdx.x) * 8;  // within I_*F_
  const int k = off & (F_ - 1);
  const size_t BF = (size_t)B_ * F_;
  u16* p = vt + (size_t)b * I_ * F_ + off;
  const float* z = zp + (size_t)b * F_ + k;
  int4 raw = *(const int4*)p;
  u16 es[8], os[8];
  *(int4*)es = raw;
#pragma unroll
  for (int j = 0; j < 8; ++j) {
    const float v = b2f(es[j]);
    float zs = 0.f;
#pragma unroll
    for (int qh = 0; qh < NQS; ++qh) zs += z[qh * BF + j];
    os[j] = f2b(v * RCP(zs));
  }
  *(int4*)p = *(int4*)os;
}

// ---------------------------------------------------------------------------
// Kernel 4: partial out over a k-half: out[q,i] = sum_{k in half} exp2(S)*v'.
// r2 skeleton (256-q tile, 64-q waves, 0.5 LDS reads/MFMA, reg-staged T14,
// proven at 904 TF = the 2-phase structural ceiling). This version amortizes
// the per-phase stage->barrier stall: DOUBLE-CHUNK phases (128 k staged per
// barrier as two 64-k sub-tiles of K and V; barriers halve 32->16) with
// sub-granular T14 (each sub's next-phase loads are issued under the other
// sub's compute; max 16 staging regs live). Q fragments hoisted direct
// global->VGPR (r4-verified), deleting the Q LDS stage + 2 barriers.
// LDS 64 KB -> still 2 blocks/CU (128 KB < 160 KB). ks=0 -> f32 out;
// ks=1 -> bf16 partial (reduce_k folds).
// ---------------------------------------------------------------------------
__global__ __launch_bounds__(256, 2) void attn_out_k(
    const u16* __restrict__ qn, const u16* __restrict__ kn,
    const u16* __restrict__ vt, float* __restrict__ out,
    u16* __restrict__ pout) {
  __shared__ __align__(16) u16 sm[32768];   // 64 KB: K dbuf 2x8192, V at 16384+

  const int t = threadIdx.x, lane = t & 63, w = t >> 6;
  const int l31 = lane & 31, lh = lane >> 5;
  // XCD-chunked decode: 16 consecutive logical ids share (b,ks).
  const int lg = swz512((int)blockIdx.x);
  const int q0 = (lg & 15) * 256, b = (lg >> 4) & 15, ks = lg >> 8;

  // hoist own 64-q B-fragments directly from global (one-time, 8 loads)
  const u16* qp = qn + ((size_t)b * F_ + q0 + w * 64 + l31) * I_ + lh * 8;
  bf16x8 qf[2][4];
#pragma unroll
  for (int qb2 = 0; qb2 < 2; ++qb2)
#pragma unroll
    for (int ic = 0; ic < 4; ++ic)
      qf[qb2][ic] = *(const bf16x8*)(qp + qb2 * 32 * I_ + ic * 16);

  // hoisted staging offsets (2 K + 2 V chunks16B per thread per 64-k sub)
  int off_l[2], kg[2], vg[2];
#pragma unroll
  for (int p = 0; p < 2; ++p) {
    const int c = p * 256 + t;
    off_l[p] = soff_l(c);
    kg[p] = soff_g(c, 64);
    vg[p] = soff_g(c, F_);
  }

  const u16* ksrc = kn + ((size_t)b * F_ + ks * (F_ / NKS)) * I_;
  const u16* vsrc = vt + (size_t)b * I_ * F_ + ks * (F_ / NKS);
  // prologue: stage phase 0 (both subs) into buffers 0
#pragma unroll
  for (int s = 0; s < 2; ++s)
#pragma unroll
    for (int p = 0; p < 2; ++p) {
      *(int4*)(sm + s * 4096 + off_l[p]) =
          *(const int4*)(ksrc + s * 64 * I_ + kg[p]);
      *(int4*)(sm + 16384 + s * 4096 + off_l[p]) =
          *(const int4*)(vsrc + s * 64 + vg[p]);
    }
  ksrc += 128 * I_;
  vsrc += 128;

  f32x16 o00 = ZERO16, o01 = ZERO16, o10 = ZERO16, o11 = ZERO16; // [qb][ih]

  auto compute64 = [&](const u16* Kc, const u16* Vc) {
    // S^T = K x Q(own 64q): rows=k (2 halves), cols=q (2 blocks)
    f32x16 s00 = ZERO16, s01 = ZERO16, s10 = ZERO16, s11 = ZERO16; // [kh][qb]
    __builtin_amdgcn_s_setprio(1);
#pragma unroll
    for (int ic = 0; ic < 4; ++ic) {
      const bf16x8 ak0 = ldfrag(Kc, l31, ic * 2 + lh);
      const bf16x8 ak1 = ldfrag(Kc + 32 * 64, l31, ic * 2 + lh);
      s00 = MFMA32(ak0, qf[0][ic], s00);
      s01 = MFMA32(ak0, qf[1][ic], s01);
      s10 = MFMA32(ak1, qf[0][ic], s10);
      s11 = MFMA32(ak1, qf[1][ic], s11);
    }
    __builtin_amdgcn_s_setprio(0);

    // exp2 + in-register transpose into PV A-fragments per q-block
    bf16x8 af[2][4];
    build_af(s00, af[0][0], af[0][1]);
    build_af(s10, af[0][2], af[0][3]);
    build_af(s01, af[1][0], af[1][1]);
    build_af(s11, af[1][2], af[1][3]);

    // O += P(64q x 64k) * V'(64k x 64i), two i-halves
    __builtin_amdgcn_s_setprio(1);
#pragma unroll
    for (int kb4 = 0; kb4 < 4; ++kb4) {
      const bf16x8 bv0 = ldfrag(Vc, l31, kb4 * 2 + lh);
      const bf16x8 bv1 = ldfrag(Vc + 32 * 64, l31, kb4 * 2 + lh);
      o00 = MFMA32(af[0][kb4], bv0, o00);
      o01 = MFMA32(af[0][kb4], bv1, o01);
      o10 = MFMA32(af[1][kb4], bv0, o10);
      o11 = MFMA32(af[1][kb4], bv1, o11);
    }
    __builtin_amdgcn_s_setprio(0);
  };

  const int NC = F_ / NKS / 128;            // 16 double-chunk phases

  for (int c = 0; c < NC; ++c) {
    const int cur = (c & 1) * 8192;
    const int nxt = cur ^ 8192;
    const bool pf = (c + 1 < NC);
    __syncthreads();                        // cur staged; nxt's readers done
    int4 kr0, kr1, vr0, vr1;
    if (pf) {                               // T14: sub0' loads under compute
      kr0 = *(const int4*)(ksrc + kg[0]);
      kr1 = *(const int4*)(ksrc + kg[1]);
      vr0 = *(const int4*)(vsrc + vg[0]);
      vr1 = *(const int4*)(vsrc + vg[1]);
    }
    compute64(sm + cur, sm + 16384 + cur);  // sub 0
    if (pf) {
      *(int4*)(sm + nxt + off_l[0])         = kr0;
      *(int4*)(sm + nxt + off_l[1])         = kr1;
      *(int4*)(sm + 16384 + nxt + off_l[0]) = vr0;
      *(int4*)(sm + 16384 + nxt + off_l[1]) = vr1;
      kr0 = *(const int4*)(ksrc + 64 * I_ + kg[0]);
      kr1 = *(const int4*)(ksrc + 64 * I_ + kg[1]);
      vr0 = *(const int4*)(vsrc + 64 + vg[0]);
      vr1 = *(const int4*)(vsrc + 64 + vg[1]);
    }
    compute64(sm + cur + 4096, sm + 16384 + cur + 4096);  // sub 1
    if (pf) {
      *(int4*)(sm + nxt + 4096 + off_l[0])         = kr0;
      *(int4*)(sm + nxt + 4096 + off_l[1])         = kr1;
      *(int4*)(sm + 16384 + nxt + 4096 + off_l[0]) = vr0;
      *(int4*)(sm + 16384 + nxt + 4096 + off_l[1]) = vr1;
      ksrc += 128 * I_;
      vsrc += 128;
    }
  }

  if (ks == 0) {
    float* ob = out + ((size_t)b * F_ + q0 + w * 64) * I_;
#pragma unroll
    for (int r = 0; r < 16; ++r) {
      const int qr = (r & 3) + 8 * (r >> 2) + 4 * lh;   // C/D row mapping
      ob[(size_t)qr * I_ + l31]              = o00[r];
      ob[(size_t)qr * I_ + 32 + l31]         = o01[r];
      ob[(size_t)(32 + qr) * I_ + l31]       = o10[r];
      ob[(size_t)(32 + qr) * I_ + 32 + l31]  = o11[r];
    }
  } else {
    u16* pb = pout + ((size_t)b * F_ + q0 + w * 64) * I_;
#pragma unroll
    for (int r = 0; r < 16; ++r) {
      const int qr = (r & 3) + 8 * (r >> 2) + 4 * lh;
      pb[(size_t)qr * I_ + l31]              = f2b(o00[r]);
      pb[(size_t)qr * I_ + 32 + l31]         = f2b(o01[r]);
      pb[(size_t)(32 + qr) * I_ + l31]       = f2b(o10[r]);
      pb[(size_t)(32 + qr) * I_ + 32 + l31]  = f2b(o11[r]);
    }
  }
}

// ---------------------------------------------------------------------------
// Kernel 5: out += bf16 partial (k-split reduction). 8 elems/thread.
// ---------------------------------------------------------------------------
__global__ __launch_bounds__(256) void reduce_k(float* __restrict__ out,
                                                const u16* __restrict__ pout) {
  const size_t i = ((size_t)blockIdx.x * 256 + threadIdx.x) * 8;
  float4 a0 = *(const float4*)(out + i);
  float4 a1 = *(const float4*)(out + i + 4);
  int4 praw = *(const int4*)(pout + i);
  u16 es[8];
  *(int4*)es = praw;
  a0.x += b2f(es[0]); a0.y += b2f(es[1]); a0.z += b2f(es[2]); a0.w += b2f(es[3]);
  a1.x += b2f(es[4]); a1.y += b2f(es[5]); a1.z += b2f(es[6]); a1.w += b2f(es[7]);
  *(float4*)(out + i)     = a0;
  *(float4*)(out + i + 4) = a1;
}

// ---------------------------------------------------------------------------
extern "C" void kernel_launch(void* const* d_in, const int* in_sizes, int n_in,
                              void* d_out, int out_size, void* d_ws,
                              size_t ws_size, hipStream_t stream) {
  const float* x  = (const float*)d_in[0];
  const float* Wq = (const float*)d_in[1];
  const float* Wk = (const float*)d_in[2];
  const float* Wv = (const float*)d_in[3];
  float* out = (float*)d_out;

  // workspace: qn, kn, vt (bf16, B*F*I each); zp (f32 [NQS][B][F]);
  //            pout (bf16 [B][F][I] k-split partial)
  const size_t NBF = (size_t)B_ * F_ * I_;
  u16* qn   = (u16*)d_ws;
  u16* kn   = qn + NBF;
  u16* vt   = kn + NBF;
  float* zp = (float*)(vt + NBF);
  u16* pout = (u16*)(zp + (size_t)NQS * B_ * F_);

  qkv_ln_k<<<dim3(F_ / 64, B_), 256, 0, stream>>>(x, Wq, Wk, Wv, qn, kn, vt);
  // 512 blocks, XCD-chunked swizzle (16 k-tiles x 16 b x NQS q-halves)
  attn_stats_k<<<dim3(512), 256, 0, stream>>>(qn, kn, zp);
  vscale_k<<<dim3(I_ * F_ / 2048, B_), 256, 0, stream>>>(vt, zp);
  // 512 blocks, XCD-chunked swizzle (16 q-tiles x 16 b x NKS k-halves)
  attn_out_k<<<dim3(512), 256, 0, stream>>>(qn, kn, vt, out, pout);
  reduce_k<<<dim3((int)(NBF / 2048)), 256, 0, stream>>>(out, pout);
}